// Round 1
// 443.355 us; speedup vs baseline: 1.0389x; 1.0389x over previous
//
#include <hip/hip_runtime.h>
#include <stdint.h>
#include <stddef.h>

// Problem constants (fixed by the reference)
#define DDIM   512
#define KCL    1024
#define BK     32
#define KSTEPS (DDIM / BK)          // 16
#define RPB    64                   // rows per block
#define THR    1024                 // threads per block (16 waves)
#define NROWS  65536
#define NBLK   (NROWS / RPB)        // 1024

#define SB_BYTES   (KCL * BK * 2)           // 65536 per B buffer (fp16) = 4096 16B chunks
#define SA_STRIDE  40                       // halves per A row (32 + 8 pad -> 80B, 16B-aligned)
#define SA_BYTES   (RPB * SA_STRIDE * 2)    // 5120 per A buffer
#define SMEM_BYTES (2 * SB_BYTES + 2 * SA_BYTES + 512)   // 141824 < 160 KiB

typedef __attribute__((ext_vector_type(4))) float    floatx4;
typedef __attribute__((ext_vector_type(2))) float    floatx2;
typedef __attribute__((ext_vector_type(8))) _Float16 half8;
typedef __attribute__((ext_vector_type(2))) _Float16 half2v;

// async global -> LDS, 16B per lane (global_load_lds_dwordx4)
__device__ __forceinline__ void gload_lds16(const void* g, void* l) {
    __builtin_amdgcn_global_load_lds(
        (const __attribute__((address_space(1))) unsigned char*)g,
        (__attribute__((address_space(3))) unsigned char*)l,
        16, 0, 0);
}

// ---------------------------------------------------------------------------
// Prep: clusters f32 [1024][512] -> wsB fp16, pre-packed per K-step tile
//   wsB[ks][c][32] with the 4 16B chunks of each (c,ks) row XOR-swizzled:
//   chunk j stored at p = (j + (c>>1)) & 3   (conflict-free B-frag ds_read_b128)
// also computes c_sq[1024]. One wave per cluster.
// ---------------------------------------------------------------------------
__global__ __launch_bounds__(256) void prep_kernel(const float* __restrict__ clusters,
                                                   _Float16* __restrict__ wsB,
                                                   float* __restrict__ csq) {
    const int l  = threadIdx.x & 63;
    const int c  = (blockIdx.x << 2) + (threadIdx.x >> 6);   // cluster 0..1023
    const int ks = l >> 2;                                   // k-step 0..15
    const int j  = l & 3;                                    // 16B chunk 0..3

    const float* src = clusters + (size_t)c * DDIM + ks * BK + j * 8;
    floatx4 f0 = *(const floatx4*)src;
    floatx4 f1 = *(const floatx4*)(src + 4);

    half8 h;
    h[0] = (_Float16)f0[0]; h[1] = (_Float16)f0[1]; h[2] = (_Float16)f0[2]; h[3] = (_Float16)f0[3];
    h[4] = (_Float16)f1[0]; h[5] = (_Float16)f1[1]; h[6] = (_Float16)f1[2]; h[7] = (_Float16)f1[3];

    const int p = (j + (c >> 1)) & 3;
    *(half8*)(wsB + (size_t)ks * (KCL * BK) + c * BK + p * 8) = h;

    float ss = f0[0]*f0[0] + f0[1]*f0[1] + f0[2]*f0[2] + f0[3]*f0[3]
             + f1[0]*f1[0] + f1[1]*f1[1] + f1[2]*f1[2] + f1[3]*f1[3];
    ss += __shfl_xor(ss, 1,  64);
    ss += __shfl_xor(ss, 2,  64);
    ss += __shfl_xor(ss, 4,  64);
    ss += __shfl_xor(ss, 8,  64);
    ss += __shfl_xor(ss, 16, 64);
    ss += __shfl_xor(ss, 32, 64);
    if (l == 0) csq[c] = ss;
}

// ---------------------------------------------------------------------------
// Main: one block = 64 rows x all 1024 clusters. 16 waves (1024 thr), wave w
// owns cols w*64..w*64+63 as 4(row) x 4(col) tiles of mfma_f32_16x16x32_f16.
// acc = 64 VGPR/wave -> <=128 total regs -> 4 waves/SIMD (16 waves/CU).
// m97-style K-loop: double-buffered LDS, tile k+1 DMA in flight during k.
// ---------------------------------------------------------------------------
__global__ __launch_bounds__(THR, 4)
void cluster_kernel(const float* __restrict__ x,
                    const _Float16* __restrict__ wsB,
                    const float* __restrict__ csq,
                    float* __restrict__ out) {
    extern __shared__ char smem[];
    char* const sB0 = smem;
    char* const sB1 = smem + SB_BYTES;
    char* const sA0 = smem + 2 * SB_BYTES;
    char* const sA1 = smem + 2 * SB_BYTES + SA_BYTES;
    float* const xsq    = (float*)(smem + 2 * SB_BYTES + 2 * SA_BYTES);        // 64 f32
    float* const rowsum = (float*)(smem + 2 * SB_BYTES + 2 * SA_BYTES + 256);  // 64 f32

    const int t      = threadIdx.x;
    const int l      = t & 63;
    const int w      = t >> 6;          // 0..15
    const int lane16 = l & 15;
    const int kgrp   = l >> 4;          // 0..3
    const int row0   = blockIdx.x * RPB;
    const int wcol   = w << 6;          // wave's first column (64-wide slice)

    if (t < 64) { xsq[t] = 0.f; rowsum[t] = 0.f; }
    __syncthreads();

    // fragment LDS byte bases (rt/ct strides folded into ds_read offset imms)
    const int abase = lane16 * (SA_STRIDE * 2) + kgrp * 16;        // + rt*1280
    const int c0    = wcol + lane16;
    const int p0    = (kgrp + (c0 >> 1)) & 3;                      // ct*16 is 0 mod 8 -> p indep of ct
    const int bbase = c0 * 64 + p0 * 16;                           // + ct*1024

    // A staging geometry: thread t loads one float2 per K-step
    const int ar = t >> 4;              // row 0..63
    const int ac = (t & 15) << 1;       // col 0,2,..,30
    const float* const aptr = x + (size_t)(row0 + ar) * DDIM + ac;
    const int awoff = ar * (SA_STRIDE * 2) + ac * 2;   // LDS byte offset

    floatx4 acc[4][4];
#pragma unroll
    for (int rt = 0; rt < 4; ++rt)
#pragma unroll
        for (int ct = 0; ct < 4; ++ct)
            acc[rt][ct] = (floatx4){0.f, 0.f, 0.f, 0.f};

    // ---- prologue: stage tile 0 into buffer 0 (full 4096 chunks: 4 x 1024)
    {
        floatx2 f = __builtin_nontemporal_load((const floatx2*)aptr);
#pragma unroll
        for (int it = 0; it < 4; ++it) {
            const int ch = it * THR + t;                 // 16B chunk 0..4095
            gload_lds16(wsB + ch * 8, sB0 + ch * 16);
        }
        half2v h;
        h[0] = (_Float16)f[0]; h[1] = (_Float16)f[1];
        *(half2v*)(sA0 + awoff) = h;
        float ss = f[0]*f[0] + f[1]*f[1];
        ss += __shfl_xor(ss, 1, 64);
        ss += __shfl_xor(ss, 2, 64);
        ss += __shfl_xor(ss, 4, 64);
        ss += __shfl_xor(ss, 8, 64);
        if ((t & 15) == 0) atomicAdd(&xsq[ar], ss);
    }

    // ---- K loop
#pragma unroll 2
    for (int k = 0; k < KSTEPS; ++k) {
        char* const sBb = (k & 1) ? sB1 : sB0;
        char* const sAb = (k & 1) ? sA1 : sA0;
        char* const sBn = (k & 1) ? sB0 : sB1;
        char* const sAn = (k & 1) ? sA0 : sA1;

        __syncthreads();                 // tile k resident (vmcnt+lgkm drained per-wave)

        floatx2 f;
        const bool more = (k + 1 < KSTEPS);
        if (more) {                      // launch tile k+1; stays in flight during compute
            // A load issued FIRST so its vmcnt wait leaves the 4 B-DMAs in flight
            f = __builtin_nontemporal_load((const floatx2*)(aptr + (k + 1) * BK));
            const _Float16* wb = wsB + (size_t)(k + 1) * (KCL * BK);
#pragma unroll
            for (int it = 0; it < 4; ++it) {
                const int ch = it * THR + t;
                gload_lds16(wb + ch * 8, sBn + ch * 16);
            }
        }

        half8 aF[4];
#pragma unroll
        for (int rt = 0; rt < 4; ++rt)
            aF[rt] = *(const half8*)(sAb + abase + rt * (16 * SA_STRIDE * 2));
#pragma unroll
        for (int ct = 0; ct < 4; ++ct) {
            const half8 bF = *(const half8*)(sBb + bbase + ct * 1024);
#pragma unroll
            for (int rt = 0; rt < 4; ++rt)
                acc[rt][ct] = __builtin_amdgcn_mfma_f32_16x16x32_f16(aF[rt], bF, acc[rt][ct], 0, 0, 0);
        }

        if (more) {                      // finish A staging for k+1 (load arrived during MFMAs)
            half2v h;
            h[0] = (_Float16)f[0]; h[1] = (_Float16)f[1];
            *(half2v*)(sAn + awoff) = h;
            float ss = f[0]*f[0] + f[1]*f[1];
            ss += __shfl_xor(ss, 1, 64);
            ss += __shfl_xor(ss, 2, 64);
            ss += __shfl_xor(ss, 4, 64);
            ss += __shfl_xor(ss, 8, 64);
            if ((t & 15) == 0) atomicAdd(&xsq[ar], ss);
        }
    }

    // ---- epilogue. C layout: col = lane&15, row = (lane>>4)*4 + reg (m89/m91)
    float cs[4];
#pragma unroll
    for (int ct = 0; ct < 4; ++ct)
        cs[ct] = csq[wcol + ct * 16 + lane16];
    floatx4 xv[4];
#pragma unroll
    for (int rt = 0; rt < 4; ++rt)
        xv[rt] = *(const floatx4*)(xsq + rt * 16 + kgrp * 4);

    float rp[4][4];
#pragma unroll
    for (int rt = 0; rt < 4; ++rt) {
#pragma unroll
        for (int i = 0; i < 4; ++i) {
            const float xr = xv[rt][i];
            float s = 0.f;
#pragma unroll
            for (int ct = 0; ct < 4; ++ct) {
                float d = xr + cs[ct] - 2.0f * acc[rt][ct][i];
                d = fmaxf(d, 0.0f);
                const float q = __builtin_amdgcn_rcpf(1.0f + d);   // ALPHA=1 -> exponent 1
                acc[rt][ct][i] = q;
                s += q;
            }
            rp[rt][i] = s;
        }
    }
    // reduce partial row sums across the 16 lanes sharing kgrp
#pragma unroll
    for (int m = 1; m <= 8; m <<= 1)
#pragma unroll
        for (int rt = 0; rt < 4; ++rt)
#pragma unroll
            for (int i = 0; i < 4; ++i)
                rp[rt][i] += __shfl_xor(rp[rt][i], m, 64);
    if (lane16 == 0) {
#pragma unroll
        for (int rt = 0; rt < 4; ++rt)
#pragma unroll
            for (int i = 0; i < 4; ++i)
                atomicAdd(&rowsum[rt * 16 + kgrp * 4 + i], rp[rt][i]);
    }
    __syncthreads();

    // plain (cached) stores: let L2 merge the 64B lane-group quadrants into
    // full lines — nt scalar dwords showed +27% WRITE_SIZE amplification
#pragma unroll
    for (int rt = 0; rt < 4; ++rt) {
        const floatx4 rs = *(const floatx4*)(rowsum + rt * 16 + kgrp * 4);
#pragma unroll
        for (int i = 0; i < 4; ++i) {
            const float inv = __builtin_amdgcn_rcpf(rs[i]);
            float* orow = out + (size_t)(row0 + rt * 16 + kgrp * 4 + i) * KCL + wcol + lane16;
#pragma unroll
            for (int ct = 0; ct < 4; ++ct)
                orow[ct * 16] = acc[rt][ct][i] * inv;
        }
    }
}

extern "C" void kernel_launch(void* const* d_in, const int* in_sizes, int n_in,
                              void* d_out, int out_size, void* d_ws, size_t ws_size,
                              hipStream_t stream) {
    (void)in_sizes; (void)n_in; (void)out_size; (void)ws_size;
    const float* x        = (const float*)d_in[0];
    const float* clusters = (const float*)d_in[1];
    float* out = (float*)d_out;

    _Float16* wsB = (_Float16*)d_ws;                                   // 1 MiB packed fp16 B
    float*    csq = (float*)((char*)d_ws + (size_t)KSTEPS * KCL * BK * 2);  // 4 KiB

    hipFuncSetAttribute((const void*)cluster_kernel,
                        hipFuncAttributeMaxDynamicSharedMemorySize, SMEM_BYTES);

    prep_kernel<<<KCL / 4, 256, 0, stream>>>(clusters, wsB, csq);
    cluster_kernel<<<NBLK, THR, SMEM_BYTES, stream>>>(x, wsB, csq, out);
}